// Round 6
// baseline (949.377 us; speedup 1.0000x reference)
//
#include <hip/hip_runtime.h>

typedef _Float16 half8 __attribute__((ext_vector_type(8)));
typedef _Float16 half4 __attribute__((ext_vector_type(4)));
typedef float f32x4 __attribute__((ext_vector_type(4)));

#define TSTEPS 255
#define R 8       // rows (batch elems) processed per block -> 512 blocks = 2/CU
#define RL 16     // LDS row dimension (MFMA tile height; rows R..15 are zero/garbage)
#define BLK 512
#define XSH 104   // xh/xl stride (halves): [h(0:64)|x(64:72)|noise(72:88)|zero(88:96)|pad]
#define ZS 260    // z2 stride (f32), interleaved cols: z'[4*hc+g] = gate g of h-col hc
#define ASH 72    // a-plane stride (halves)

__device__ __forceinline__ float frcp(float x) { return __builtin_amdgcn_rcpf(x); }

__device__ __forceinline__ f32x4 mfma16(half8 a, half8 b, f32x4 c) {
  return __builtin_amdgcn_mfma_f32_16x16x32_f16(a, b, c, 0, 0, 0);
}

__global__ __launch_bounds__(BLK)
void genlstm_kernel(const float* __restrict__ noise,
                    const float* __restrict__ eps,
                    const float* __restrict__ Wx,
                    const float* __restrict__ Wh,
                    const float* __restrict__ bg,
                    const float* __restrict__ Wm1, const float* __restrict__ bm1,
                    const float* __restrict__ Wm2, const float* __restrict__ bm2,
                    const float* __restrict__ Wm3, const float* __restrict__ bm3,
                    const float* __restrict__ Wv1, const float* __restrict__ bv1,
                    const float* __restrict__ Wv2, const float* __restrict__ bv2,
                    const float* __restrict__ Wv3, const float* __restrict__ bv3,
                    float* __restrict__ out)
{
  __shared__ __align__(16) _Float16 xh[RL][XSH];
  __shared__ __align__(16) _Float16 xl[RL][XSH];
  __shared__ __align__(16) float    z2[RL][ZS];
  __shared__ __align__(16) _Float16 a1h[2][RL][ASH];
  __shared__ __align__(16) _Float16 a1l[2][RL][ASH];
  __shared__ __align__(16) _Float16 a2h[2][RL][ASH];
  __shared__ __align__(16) _Float16 a2l[2][RL][ASH];
  __shared__ __align__(16) float    mulv[2][RL][12];

  const int tid  = threadIdx.x;
  const int w    = tid >> 6;   // wave 0..7
  const int l    = tid & 63;
  const int lrow = l & 15;     // tile row/col within 16x16
  const int lq   = l >> 4;     // k-group (8 elems)
  const long rowbase = (long)blockIdx.x * R;

  // ---------- one-time weight fragment staging ----------
  // Gate B: staged col jc -> original gate col 64*(jc&3) + (jc>>2)  (z' interleave);
  // k reordered: [Wh rows 0..63 | Wx rows 0..23 | zeros]
  half8 gBhi[2][3], gBlo[2][3];
  #pragma unroll
  for (int t = 0; t < 2; ++t)
    #pragma unroll
    for (int kt = 0; kt < 3; ++kt)
      #pragma unroll
      for (int j = 0; j < 8; ++j) {
        int k  = 32 * kt + 8 * lq + j;
        int jc = 32 * w + 16 * t + lrow;
        int n  = 64 * (jc & 3) + (jc >> 2);
        float v = 0.f;
        if (k < 64) v = Wh[k * 256 + n];
        else if (k < 88) v = Wx[(k - 64) * 256 + n];
        _Float16 h = (_Float16)v;
        gBhi[t][kt][j] = h;
        gBlo[t][kt][j] = (_Float16)(v - (float)h);
      }

  // MLP tiles: chain = w>>2 (0:mu 1:var), N-tile nt = w&3
  const int chain = w >> 2;
  const int nt = w & 3;
  const float* W1 = chain ? Wv1 : Wm1;
  const float* W2 = chain ? Wv2 : Wm2;
  half8 B1hi[2], B1lo[2], B2hi[2], B2lo[2];
  #pragma unroll
  for (int kt = 0; kt < 2; ++kt)
    #pragma unroll
    for (int j = 0; j < 8; ++j) {
      int k = 32 * kt + 8 * lq + j;
      int n = 16 * nt + lrow;
      float v1 = W1[k * 64 + n];
      _Float16 h1 = (_Float16)v1;
      B1hi[kt][j] = h1; B1lo[kt][j] = (_Float16)(v1 - (float)h1);
      float v2 = W2[k * 64 + n];
      _Float16 h2 = (_Float16)v2;
      B2hi[kt][j] = h2; B2lo[kt][j] = (_Float16)(v2 - (float)h2);
    }

  // Heads: wave 0 mu, wave 1 logvar
  half8 B3hi[2], B3lo[2];
  if (w < 2) {
    const float* W3 = w ? Wv3 : Wm3;
    #pragma unroll
    for (int kt = 0; kt < 2; ++kt)
      #pragma unroll
      for (int j = 0; j < 8; ++j) {
        int k = 32 * kt + 8 * lq + j;
        float v = (lrow < 8) ? W3[k * 8 + lrow] : 0.f;
        _Float16 h = (_Float16)v;
        B3hi[kt][j] = h;
        B3lo[kt][j] = (_Float16)(v - (float)h);
      }
  }

  const float bias1 = (chain ? bv1 : bm1)[16 * nt + lrow];
  const float bias2 = (chain ? bv2 : bm2)[16 * nt + lrow];
  float bias3 = 0.f;
  if (w < 2 && lrow < 8) bias3 = (w ? bv3 : bm3)[lrow];

  // gate biases as float4 matching z' float4 read: {i,f,g,o} of h-col l
  const float4 bgq = {bg[l], bg[64 + l], bg[128 + l], bg[192 + l]};

  float cst0 = 0.f;                        // c-state: row w, h-col l
  const int r5 = tid >> 3, d5 = tid & 7;   // sampler mapping (threads < 64)
  float cum = 0.f;

  // persistent h fragments (h0 = 0); reloaded each step in S2, reused in next S0
  half8 hHi[2], hLo[2];
  #pragma unroll
  for (int kt = 0; kt < 2; ++kt)
    #pragma unroll
    for (int j = 0; j < 8; ++j) { hHi[kt][j] = (_Float16)0; hLo[kt][j] = (_Float16)0; }

  // ---------- prologue ----------
  for (int i = tid; i < RL * XSH; i += BLK) {
    (&xh[0][0])[i] = (_Float16)0;
    (&xl[0][0])[i] = (_Float16)0;
  }
  if (tid < 64) out[((rowbase + r5) * 256) * 8 + d5] = 0.f;  // cumsum row 0
  __syncthreads();

  float4 nz = {0.f, 0.f, 0.f, 0.f};
  if (tid < 32) {
    int r = tid >> 2, j4 = (tid & 3) * 4;
    float4 n0 = *(const float4*)&noise[((rowbase + r) * TSTEPS) * 16 + j4];
    float tmp[4] = {n0.x, n0.y, n0.z, n0.w};
    half4 nh, nl;
    #pragma unroll
    for (int j = 0; j < 4; ++j) {
      _Float16 h = (_Float16)tmp[j];
      nh[j] = h; nl[j] = (_Float16)(tmp[j] - (float)h);
    }
    *(half4*)&xh[r][72 + j4] = nh;
    *(half4*)&xl[r][72 + j4] = nl;
    nz = *(const float4*)&noise[((rowbase + r) * TSTEPS + 1) * 16 + j4];
  }
  float ev = 0.f;
  if (tid < 64) ev = eps[((rowbase + r5) * TSTEPS) * 8 + d5];
  __syncthreads();

  // ---------- time loop ----------
  for (int ts = 0; ts < TSTEPS; ++ts) {
    // S0: gate MFMA. h-frags (kt 0,1) from registers; x|noise frag fresh.
    half8 Xhi = *(const half8*)&xh[lrow][64 + 8 * lq];
    half8 Xlo = *(const half8*)&xl[lrow][64 + 8 * lq];

    f32x4 accz0 = {0.f, 0.f, 0.f, 0.f};
    f32x4 accz1 = {0.f, 0.f, 0.f, 0.f};
    accz0 = mfma16(hHi[0], gBhi[0][0], accz0);
    accz1 = mfma16(hHi[0], gBhi[1][0], accz1);
    accz0 = mfma16(hLo[0], gBhi[0][0], accz0);
    accz1 = mfma16(hLo[0], gBhi[1][0], accz1);
    accz0 = mfma16(hHi[0], gBlo[0][0], accz0);
    accz1 = mfma16(hHi[0], gBlo[1][0], accz1);
    accz0 = mfma16(hHi[1], gBhi[0][1], accz0);
    accz1 = mfma16(hHi[1], gBhi[1][1], accz1);
    accz0 = mfma16(hLo[1], gBhi[0][1], accz0);
    accz1 = mfma16(hLo[1], gBhi[1][1], accz1);
    accz0 = mfma16(hHi[1], gBlo[0][1], accz0);
    accz1 = mfma16(hHi[1], gBlo[1][1], accz1);
    accz0 = mfma16(Xhi, gBhi[0][2], accz0);
    accz1 = mfma16(Xhi, gBhi[1][2], accz1);
    accz0 = mfma16(Xlo, gBhi[0][2], accz0);
    accz1 = mfma16(Xlo, gBhi[1][2], accz1);
    accz0 = mfma16(Xhi, gBlo[0][2], accz0);
    accz1 = mfma16(Xhi, gBlo[1][2], accz1);
    {
      const int r0 = 4 * lq;
      #pragma unroll
      for (int k = 0; k < 4; ++k) {
        z2[r0 + k][32 * w + lrow]      = accz0[k];
        z2[r0 + k][32 * w + 16 + lrow] = accz1[k];
      }
    }
    __syncthreads();  // A: z' complete

    // S1: gates -> c,h (row w; h-col l); one float4 read
    {
      const int r = w;
      float4 zq = *(const float4*)&z2[r][4 * l];
      float zi = zq.x + bgq.x;
      float zf = zq.y + bgq.y;
      float zg = zq.z + bgq.z;
      float zo = zq.w + bgq.w;
      float si = frcp(1.f + __expf(-zi));
      float sf = frcp(1.f + __expf(-zf));
      float so = frcp(1.f + __expf(-zo));
      float ag = fabsf(zg), eg = __expf(-2.f * ag);
      float tg = copysignf((1.f - eg) * frcp(1.f + eg), zg);
      cst0 = fmaf(sf, cst0, si * tg);
      float ac = fabsf(cst0), ec = __expf(-2.f * ac);
      float tc = copysignf((1.f - ec) * frcp(1.f + ec), cst0);
      float hv = so * tc;
      _Float16 hh = (_Float16)hv;
      xh[r][l] = hh;
      xl[r][l] = (_Float16)(hv - (float)hh);
    }
    if (tid < 32) {   // noise[ts+1] into planes; prefetch noise[ts+2]
      int r = tid >> 2, j4 = (tid & 3) * 4;
      float tmp[4] = {nz.x, nz.y, nz.z, nz.w};
      half4 nh, nl;
      #pragma unroll
      for (int j = 0; j < 4; ++j) {
        _Float16 h = (_Float16)tmp[j];
        nh[j] = h; nl[j] = (_Float16)(tmp[j] - (float)h);
      }
      *(half4*)&xh[r][72 + j4] = nh;
      *(half4*)&xl[r][72 + j4] = nl;
      if (ts + 2 < TSTEPS)
        nz = *(const float4*)&noise[((rowbase + r) * TSTEPS + ts + 2) * 16 + j4];
    }
    __syncthreads();  // B: h, next noise in planes

    // S2: MLP layer 1 (loads h frags -> kept for next S0)
    {
      hHi[0] = *(const half8*)&xh[lrow][8 * lq];
      hHi[1] = *(const half8*)&xh[lrow][32 + 8 * lq];
      hLo[0] = *(const half8*)&xl[lrow][8 * lq];
      hLo[1] = *(const half8*)&xl[lrow][32 + 8 * lq];
      f32x4 acc = {0.f, 0.f, 0.f, 0.f};
      #pragma unroll
      for (int kt = 0; kt < 2; ++kt) {
        acc = mfma16(hHi[kt], B1hi[kt], acc);
        acc = mfma16(hLo[kt], B1hi[kt], acc);
        acc = mfma16(hHi[kt], B1lo[kt], acc);
      }
      const int r0 = 4 * lq;
      #pragma unroll
      for (int k = 0; k < 4; ++k) {
        float v = fmaxf(acc[k] + bias1, 0.f);
        _Float16 vh = (_Float16)v;
        a1h[chain][r0 + k][16 * nt + lrow] = vh;
        a1l[chain][r0 + k][16 * nt + lrow] = (_Float16)(v - (float)vh);
      }
    }
    __syncthreads();  // C

    // S3: MLP layer 2
    {
      half8 ahi0 = *(const half8*)&a1h[chain][lrow][8 * lq];
      half8 ahi1 = *(const half8*)&a1h[chain][lrow][32 + 8 * lq];
      half8 alo0 = *(const half8*)&a1l[chain][lrow][8 * lq];
      half8 alo1 = *(const half8*)&a1l[chain][lrow][32 + 8 * lq];
      f32x4 acc = {0.f, 0.f, 0.f, 0.f};
      acc = mfma16(ahi0, B2hi[0], acc);
      acc = mfma16(alo0, B2hi[0], acc);
      acc = mfma16(ahi0, B2lo[0], acc);
      acc = mfma16(ahi1, B2hi[1], acc);
      acc = mfma16(alo1, B2hi[1], acc);
      acc = mfma16(ahi1, B2lo[1], acc);
      const int r0 = 4 * lq;
      #pragma unroll
      for (int k = 0; k < 4; ++k) {
        float v = fmaxf(acc[k] + bias2, 0.f);
        _Float16 vh = (_Float16)v;
        a2h[chain][r0 + k][16 * nt + lrow] = vh;
        a2l[chain][r0 + k][16 * nt + lrow] = (_Float16)(v - (float)vh);
      }
    }
    __syncthreads();  // D

    // S4: heads (wave 0: mu, wave 1: logvar)
    if (w < 2) {
      half8 chi0 = *(const half8*)&a2h[w][lrow][8 * lq];
      half8 chi1 = *(const half8*)&a2h[w][lrow][32 + 8 * lq];
      half8 clo0 = *(const half8*)&a2l[w][lrow][8 * lq];
      half8 clo1 = *(const half8*)&a2l[w][lrow][32 + 8 * lq];
      f32x4 acc = {0.f, 0.f, 0.f, 0.f};
      acc = mfma16(chi0, B3hi[0], acc);
      acc = mfma16(clo0, B3hi[0], acc);
      acc = mfma16(chi0, B3lo[0], acc);
      acc = mfma16(chi1, B3hi[1], acc);
      acc = mfma16(clo1, B3hi[1], acc);
      acc = mfma16(chi1, B3lo[1], acc);
      if (lrow < 8) {
        const int r0 = 4 * lq;
        #pragma unroll
        for (int k = 0; k < 4; ++k)
          mulv[w][r0 + k][lrow] = acc[k] + bias3;
      }
    }
    __syncthreads();  // E

    // S5: sample, cumsum, output, x feedback (threads < 64)
    if (tid < 64) {
      float mu = mulv[0][r5][d5];
      float lv = mulv[1][r5][d5];
      float x = fmaf(__expf(0.5f * lv), ev, mu);
      cum += x;
      out[((rowbase + r5) * 256 + ts + 1) * 8 + d5] = cum;
      _Float16 xhh = (_Float16)x;
      xh[r5][64 + d5] = xhh;
      xl[r5][64 + d5] = (_Float16)(x - (float)xhh);
      if (ts + 1 < TSTEPS)
        ev = eps[((rowbase + r5) * TSTEPS + ts + 1) * 8 + d5];
    }
    __syncthreads();  // F
  }
}

extern "C" void kernel_launch(void* const* d_in, const int* in_sizes, int n_in,
                              void* d_out, int out_size, void* d_ws, size_t ws_size,
                              hipStream_t stream) {
  const float* noise = (const float*)d_in[0];
  const float* eps   = (const float*)d_in[1];
  const float* Wx    = (const float*)d_in[2];
  const float* Wh    = (const float*)d_in[3];
  const float* bg    = (const float*)d_in[4];
  const float* Wm1   = (const float*)d_in[5];
  const float* bm1   = (const float*)d_in[6];
  const float* Wm2   = (const float*)d_in[7];
  const float* bm2   = (const float*)d_in[8];
  const float* Wm3   = (const float*)d_in[9];
  const float* bm3   = (const float*)d_in[10];
  const float* Wv1   = (const float*)d_in[11];
  const float* bv1   = (const float*)d_in[12];
  const float* Wv2   = (const float*)d_in[13];
  const float* bv2   = (const float*)d_in[14];
  const float* Wv3   = (const float*)d_in[15];
  const float* bv3   = (const float*)d_in[16];
  float* out = (float*)d_out;

  dim3 grid(4096 / R), block(BLK);
  hipLaunchKernelGGL(genlstm_kernel, grid, block, 0, stream,
                     noise, eps, Wx, Wh, bg, Wm1, bm1, Wm2, bm2, Wm3, bm3,
                     Wv1, bv1, Wv2, bv2, Wv3, bv3, out);
}

// Round 7
// 626.214 us; speedup vs baseline: 1.5161x; 1.5161x over previous
//
#include <hip/hip_runtime.h>

typedef _Float16 half8 __attribute__((ext_vector_type(8)));
typedef _Float16 half4 __attribute__((ext_vector_type(4)));
typedef unsigned short ushort8 __attribute__((ext_vector_type(8)));
typedef float f32x4 __attribute__((ext_vector_type(4)));

#define TSTEPS 255
#define R 16
#define BLK 512
#define XSH 104   // xh/xl stride: [h(0:64)|x(64:72,unused/zero)|noise(72:88)|zero(88:96)|pad]
#define ZS 260    // z2 stride (f32), interleaved: z'[4*hc+g] = gate g of h-col hc
#define ASH 72    // a-plane stride (halves)

__device__ __forceinline__ float frcp(float x) { return __builtin_amdgcn_rcpf(x); }

__device__ __forceinline__ f32x4 mfma16(half8 a, half8 b, f32x4 c) {
  return __builtin_amdgcn_mfma_f32_16x16x32_f16(a, b, c, 0, 0, 0);
}

// pack x into (hi f16 | lo f16) dword
__device__ __forceinline__ unsigned int packhl(float x) {
  _Float16 hh = (_Float16)x;
  _Float16 hl = (_Float16)(x - (float)hh);
  return (unsigned int)__builtin_bit_cast(unsigned short, hh) |
         ((unsigned int)__builtin_bit_cast(unsigned short, hl) << 16);
}

__global__ __launch_bounds__(BLK)
void genlstm_kernel(const float* __restrict__ noise,
                    const float* __restrict__ eps,
                    const float* __restrict__ Wx,
                    const float* __restrict__ Wh,
                    const float* __restrict__ bg,
                    const float* __restrict__ Wm1, const float* __restrict__ bm1,
                    const float* __restrict__ Wm2, const float* __restrict__ bm2,
                    const float* __restrict__ Wm3, const float* __restrict__ bm3,
                    const float* __restrict__ Wv1, const float* __restrict__ bv1,
                    const float* __restrict__ Wv2, const float* __restrict__ bv2,
                    const float* __restrict__ Wv3, const float* __restrict__ bv3,
                    float* __restrict__ out)
{
  __shared__ __align__(16) _Float16 xh[R][XSH];
  __shared__ __align__(16) _Float16 xl[R][XSH];
  __shared__ __align__(16) float    z2[R][ZS];
  __shared__ __align__(16) _Float16 a1h[2][R][ASH];
  __shared__ __align__(16) _Float16 a1l[2][R][ASH];
  __shared__ __align__(16) _Float16 a2h[2][R][ASH];
  __shared__ __align__(16) _Float16 a2l[2][R][ASH];

  const int tid  = threadIdx.x;
  const int w    = tid >> 6;   // wave 0..7
  const int l    = tid & 63;
  const int lrow = l & 15;     // tile row/col within 16x16
  const int lq   = l >> 4;     // k-group (8 elems)
  const long rowbase = (long)blockIdx.x * R;

  // ---------- one-time weight fragment staging ----------
  // Gate B: staged col jc -> original gate col 64*(jc&3)+(jc>>2)  (z' interleave);
  // k reordered: [Wh rows 0..63 | Wx rows 0..23 (x 0..7, noise 8..23) | zeros]
  half8 gBhi[2][3], gBlo[2][3];
  #pragma unroll
  for (int t = 0; t < 2; ++t)
    #pragma unroll
    for (int kt = 0; kt < 3; ++kt)
      #pragma unroll
      for (int j = 0; j < 8; ++j) {
        int k  = 32 * kt + 8 * lq + j;
        int jc = 32 * w + 16 * t + lrow;
        int n  = 64 * (jc & 3) + (jc >> 2);
        float v = 0.f;
        if (k < 64) v = Wh[k * 256 + n];
        else if (k < 88) v = Wx[(k - 64) * 256 + n];
        _Float16 h = (_Float16)v;
        gBhi[t][kt][j] = h;
        gBlo[t][kt][j] = (_Float16)(v - (float)h);
      }

  // MLP tiles: chain = w>>2 (0:mu 1:var), N-tile nt = w&3
  const int chain = w >> 2;
  const int nt = w & 3;
  const float* W1 = chain ? Wv1 : Wm1;
  const float* W2 = chain ? Wv2 : Wm2;
  half8 B1hi[2], B1lo[2], B2hi[2], B2lo[2];
  #pragma unroll
  for (int kt = 0; kt < 2; ++kt)
    #pragma unroll
    for (int j = 0; j < 8; ++j) {
      int k = 32 * kt + 8 * lq + j;
      int n = 16 * nt + lrow;
      float v1 = W1[k * 64 + n];
      _Float16 h1 = (_Float16)v1;
      B1hi[kt][j] = h1; B1lo[kt][j] = (_Float16)(v1 - (float)h1);
      float v2 = W2[k * 64 + n];
      _Float16 h2 = (_Float16)v2;
      B2hi[kt][j] = h2; B2lo[kt][j] = (_Float16)(v2 - (float)h2);
    }

  // Transposed heads (ALL waves, redundant): A = W3^T zero-padded to 16 rows.
  // A[d][k] = W3[k*8+d] for d<8 else 0;  frag elem: k = 32kt+8lq+j, row = lrow.
  half8 Amhi[2], Amlo[2], Avhi[2], Avlo[2];
  #pragma unroll
  for (int kt = 0; kt < 2; ++kt)
    #pragma unroll
    for (int j = 0; j < 8; ++j) {
      int k = 32 * kt + 8 * lq + j;
      float vm = (lrow < 8) ? Wm3[k * 8 + lrow] : 0.f;
      _Float16 hm = (_Float16)vm;
      Amhi[kt][j] = hm; Amlo[kt][j] = (_Float16)(vm - (float)hm);
      float vv = (lrow < 8) ? Wv3[k * 8 + lrow] : 0.f;
      _Float16 hv = (_Float16)vv;
      Avhi[kt][j] = hv; Avlo[kt][j] = (_Float16)(vv - (float)hv);
    }

  const float bias1 = (chain ? bv1 : bm1)[16 * nt + lrow];
  const float bias2 = (chain ? bv2 : bm2)[16 * nt + lrow];

  // head bias + eps mapping: lane (lq,lrow) owns (r=lrow, d=4*(lq&1)+k), valid lq<2
  const int d0 = 4 * (lq & 1);
  const float4 bm3q = *(const float4*)&bm3[d0];
  const float4 bv3q = *(const float4*)&bv3[d0];

  // gate biases as float4 matching z' float4 read: {i,f,g,o} of h-col l
  const float4 bgq = {bg[l], bg[64 + l], bg[128 + l], bg[192 + l]};

  float cst0 = 0.f, cst1 = 0.f;   // c-state rows w, w+8, h-col l

  // sampler state (per lane; meaningful for lq<2)
  f32x4 cum4 = {0.f, 0.f, 0.f, 0.f};
  float4 ep4 = {0.f, 0.f, 0.f, 0.f};
  unsigned int pk0 = 0, pk1 = 0, pk2 = 0, pk3 = 0;  // packed x (hi|lo), x0 = 0

  // persistent h fragments (h0 = 0); loaded in S2, reused in next S0
  half8 hHi[2], hLo[2];
  #pragma unroll
  for (int kt = 0; kt < 2; ++kt)
    #pragma unroll
    for (int j = 0; j < 8; ++j) { hHi[kt][j] = (_Float16)0; hLo[kt][j] = (_Float16)0; }

  // ---------- prologue ----------
  for (int i = tid; i < R * XSH; i += BLK) {
    (&xh[0][0])[i] = (_Float16)0;
    (&xl[0][0])[i] = (_Float16)0;
  }
  {
    const int r5 = tid >> 3, d5 = tid & 7;
    if (tid < 128) out[((rowbase + r5) * 256) * 8 + d5] = 0.f;  // cumsum row 0
  }

  float4 nz = {0.f, 0.f, 0.f, 0.f};
  if (tid < 64) {
    int r = tid >> 2, j4 = (tid & 3) * 4;
    float4 n0 = *(const float4*)&noise[((rowbase + r) * TSTEPS) * 16 + j4];
    float tmp[4] = {n0.x, n0.y, n0.z, n0.w};
    half4 nh, nl;
    #pragma unroll
    for (int j = 0; j < 4; ++j) {
      _Float16 h = (_Float16)tmp[j];
      nh[j] = h; nl[j] = (_Float16)(tmp[j] - (float)h);
    }
    *(half4*)&xh[r][72 + j4] = nh;
    *(half4*)&xl[r][72 + j4] = nl;
    nz = *(const float4*)&noise[((rowbase + r) * TSTEPS + 1) * 16 + j4];
  }
  if (lq < 2) ep4 = *(const float4*)&eps[((rowbase + lrow) * TSTEPS) * 8 + d0];
  __syncthreads();

  // ---------- time loop: 4 barriers/step ----------
  for (int ts = 0; ts < TSTEPS; ++ts) {
    // ---- S0: gate MFMA. h-frags from regs; x from pk regs (shuffle); noise from LDS.
    half8 Xhi = *(const half8*)&xh[lrow][64 + 8 * lq];
    half8 Xlo = *(const half8*)&xl[lrow][64 + 8 * lq];
    {
      unsigned int up0 = (unsigned int)__shfl_down((int)pk0, 16);
      unsigned int up1 = (unsigned int)__shfl_down((int)pk1, 16);
      unsigned int up2 = (unsigned int)__shfl_down((int)pk2, 16);
      unsigned int up3 = (unsigned int)__shfl_down((int)pk3, 16);
      if (lq == 0) {
        ushort8 uh, ul;
        uh[0] = (unsigned short)pk0; ul[0] = (unsigned short)(pk0 >> 16);
        uh[1] = (unsigned short)pk1; ul[1] = (unsigned short)(pk1 >> 16);
        uh[2] = (unsigned short)pk2; ul[2] = (unsigned short)(pk2 >> 16);
        uh[3] = (unsigned short)pk3; ul[3] = (unsigned short)(pk3 >> 16);
        uh[4] = (unsigned short)up0; ul[4] = (unsigned short)(up0 >> 16);
        uh[5] = (unsigned short)up1; ul[5] = (unsigned short)(up1 >> 16);
        uh[6] = (unsigned short)up2; ul[6] = (unsigned short)(up2 >> 16);
        uh[7] = (unsigned short)up3; ul[7] = (unsigned short)(up3 >> 16);
        Xhi = __builtin_bit_cast(half8, uh);
        Xlo = __builtin_bit_cast(half8, ul);
      }
    }

    f32x4 accz0 = {0.f, 0.f, 0.f, 0.f};
    f32x4 accz1 = {0.f, 0.f, 0.f, 0.f};
    accz0 = mfma16(hHi[0], gBhi[0][0], accz0);
    accz1 = mfma16(hHi[0], gBhi[1][0], accz1);
    accz0 = mfma16(hLo[0], gBhi[0][0], accz0);
    accz1 = mfma16(hLo[0], gBhi[1][0], accz1);
    accz0 = mfma16(hHi[0], gBlo[0][0], accz0);
    accz1 = mfma16(hHi[0], gBlo[1][0], accz1);
    accz0 = mfma16(hHi[1], gBhi[0][1], accz0);
    accz1 = mfma16(hHi[1], gBhi[1][1], accz1);
    accz0 = mfma16(hLo[1], gBhi[0][1], accz0);
    accz1 = mfma16(hLo[1], gBhi[1][1], accz1);
    accz0 = mfma16(hHi[1], gBlo[0][1], accz0);
    accz1 = mfma16(hHi[1], gBlo[1][1], accz1);
    accz0 = mfma16(Xhi, gBhi[0][2], accz0);
    accz1 = mfma16(Xhi, gBhi[1][2], accz1);
    accz0 = mfma16(Xlo, gBhi[0][2], accz0);
    accz1 = mfma16(Xlo, gBhi[1][2], accz1);
    accz0 = mfma16(Xhi, gBlo[0][2], accz0);
    accz1 = mfma16(Xhi, gBlo[1][2], accz1);
    {
      const int r0 = 4 * lq;
      #pragma unroll
      for (int k = 0; k < 4; ++k) {
        z2[r0 + k][32 * w + lrow]      = accz0[k];
        z2[r0 + k][32 * w + 16 + lrow] = accz1[k];
      }
    }
    __syncthreads();  // A: z' complete

    // ---- S1: gates -> c,h (rows w, w+8; h-col l) + noise feed
    #pragma unroll
    for (int rr = 0; rr < 2; ++rr) {
      const int r = w + rr * 8;
      float4 zq = *(const float4*)&z2[r][4 * l];
      float zi = zq.x + bgq.x;
      float zf = zq.y + bgq.y;
      float zg = zq.z + bgq.z;
      float zo = zq.w + bgq.w;
      float si = frcp(1.f + __expf(-zi));
      float sf = frcp(1.f + __expf(-zf));
      float so = frcp(1.f + __expf(-zo));
      float ag = fabsf(zg), eg = __expf(-2.f * ag);
      float tg = copysignf((1.f - eg) * frcp(1.f + eg), zg);
      float cs = rr ? cst1 : cst0;
      cs = fmaf(sf, cs, si * tg);
      if (rr) cst1 = cs; else cst0 = cs;
      float ac = fabsf(cs), ec = __expf(-2.f * ac);
      float tc = copysignf((1.f - ec) * frcp(1.f + ec), cs);
      float hv = so * tc;
      _Float16 hh = (_Float16)hv;
      xh[r][l] = hh;
      xl[r][l] = (_Float16)(hv - (float)hh);
    }
    if (tid < 64) {   // noise[ts+1] into planes; prefetch noise[ts+2]
      int r = tid >> 2, j4 = (tid & 3) * 4;
      float tmp[4] = {nz.x, nz.y, nz.z, nz.w};
      half4 nh, nl;
      #pragma unroll
      for (int j = 0; j < 4; ++j) {
        _Float16 h = (_Float16)tmp[j];
        nh[j] = h; nl[j] = (_Float16)(tmp[j] - (float)h);
      }
      *(half4*)&xh[r][72 + j4] = nh;
      *(half4*)&xl[r][72 + j4] = nl;
      if (ts + 2 < TSTEPS)
        nz = *(const float4*)&noise[((rowbase + r) * TSTEPS + ts + 2) * 16 + j4];
    }
    __syncthreads();  // B: h, next noise in planes

    // ---- S2: MLP layer 1 (h frags kept for next S0)
    {
      hHi[0] = *(const half8*)&xh[lrow][8 * lq];
      hHi[1] = *(const half8*)&xh[lrow][32 + 8 * lq];
      hLo[0] = *(const half8*)&xl[lrow][8 * lq];
      hLo[1] = *(const half8*)&xl[lrow][32 + 8 * lq];
      f32x4 acc = {0.f, 0.f, 0.f, 0.f};
      #pragma unroll
      for (int kt = 0; kt < 2; ++kt) {
        acc = mfma16(hHi[kt], B1hi[kt], acc);
        acc = mfma16(hLo[kt], B1hi[kt], acc);
        acc = mfma16(hHi[kt], B1lo[kt], acc);
      }
      const int r0 = 4 * lq;
      #pragma unroll
      for (int k = 0; k < 4; ++k) {
        float v = fmaxf(acc[k] + bias1, 0.f);
        _Float16 vh = (_Float16)v;
        a1h[chain][r0 + k][16 * nt + lrow] = vh;
        a1l[chain][r0 + k][16 * nt + lrow] = (_Float16)(v - (float)vh);
      }
    }
    __syncthreads();  // C

    // ---- S3: MLP layer 2
    {
      half8 ahi0 = *(const half8*)&a1h[chain][lrow][8 * lq];
      half8 ahi1 = *(const half8*)&a1h[chain][lrow][32 + 8 * lq];
      half8 alo0 = *(const half8*)&a1l[chain][lrow][8 * lq];
      half8 alo1 = *(const half8*)&a1l[chain][lrow][32 + 8 * lq];
      f32x4 acc = {0.f, 0.f, 0.f, 0.f};
      acc = mfma16(ahi0, B2hi[0], acc);
      acc = mfma16(alo0, B2hi[0], acc);
      acc = mfma16(ahi0, B2lo[0], acc);
      acc = mfma16(ahi1, B2hi[1], acc);
      acc = mfma16(alo1, B2hi[1], acc);
      acc = mfma16(ahi1, B2lo[1], acc);
      const int r0 = 4 * lq;
      #pragma unroll
      for (int k = 0; k < 4; ++k) {
        float v = fmaxf(acc[k] + bias2, 0.f);
        _Float16 vh = (_Float16)v;
        a2h[chain][r0 + k][16 * nt + lrow] = vh;
        a2l[chain][r0 + k][16 * nt + lrow] = (_Float16)(v - (float)vh);
      }
    }
    __syncthreads();  // D: a2 complete  (last barrier of the step)

    // ---- S4: transposed heads, redundant on ALL waves.
    // C: row = dim d (4lq+k, valid d<8), col = batch row r = lrow.
    f32x4 accm = {0.f, 0.f, 0.f, 0.f};
    f32x4 accv = {0.f, 0.f, 0.f, 0.f};
    {
      half8 b0h0 = *(const half8*)&a2h[0][lrow][8 * lq];
      half8 b0h1 = *(const half8*)&a2h[0][lrow][32 + 8 * lq];
      half8 b0l0 = *(const half8*)&a2l[0][lrow][8 * lq];
      half8 b0l1 = *(const half8*)&a2l[0][lrow][32 + 8 * lq];
      accm = mfma16(Amhi[0], b0h0, accm);
      accm = mfma16(Amlo[0], b0h0, accm);
      accm = mfma16(Amhi[0], b0l0, accm);
      accm = mfma16(Amhi[1], b0h1, accm);
      accm = mfma16(Amlo[1], b0h1, accm);
      accm = mfma16(Amhi[1], b0l1, accm);
      half8 b1h0 = *(const half8*)&a2h[1][lrow][8 * lq];
      half8 b1h1 = *(const half8*)&a2h[1][lrow][32 + 8 * lq];
      half8 b1l0 = *(const half8*)&a2l[1][lrow][8 * lq];
      half8 b1l1 = *(const half8*)&a2l[1][lrow][32 + 8 * lq];
      accv = mfma16(Avhi[0], b1h0, accv);
      accv = mfma16(Avlo[0], b1h0, accv);
      accv = mfma16(Avhi[0], b1l0, accv);
      accv = mfma16(Avhi[1], b1h1, accv);
      accv = mfma16(Avlo[1], b1h1, accv);
      accv = mfma16(Avhi[1], b1l1, accv);
    }

    // ---- S5: sample + cumsum + out (wave 0) + pack x into regs for next S0
    {
      float x0v = fmaf(__expf(0.5f * (accv[0] + bv3q.x)), ep4.x, accm[0] + bm3q.x);
      float x1v = fmaf(__expf(0.5f * (accv[1] + bv3q.y)), ep4.y, accm[1] + bm3q.y);
      float x2v = fmaf(__expf(0.5f * (accv[2] + bv3q.z)), ep4.z, accm[2] + bm3q.z);
      float x3v = fmaf(__expf(0.5f * (accv[3] + bv3q.w)), ep4.w, accm[3] + bm3q.w);
      cum4[0] += x0v; cum4[1] += x1v; cum4[2] += x2v; cum4[3] += x3v;
      if (w == 0 && lq < 2) {
        float4 cv = {cum4[0], cum4[1], cum4[2], cum4[3]};
        *(float4*)&out[((rowbase + lrow) * 256 + ts + 1) * 8 + d0] = cv;
      }
      pk0 = packhl(x0v);
      pk1 = packhl(x1v);
      pk2 = packhl(x2v);
      pk3 = packhl(x3v);
      if (ts + 1 < TSTEPS && lq < 2)
        ep4 = *(const float4*)&eps[((rowbase + lrow) * TSTEPS + ts + 1) * 8 + d0];
    }
    // no barrier: x lives in registers; next S0's LDS reads are all
    // regions written before barrier B/C/D of this step.
  }
}

extern "C" void kernel_launch(void* const* d_in, const int* in_sizes, int n_in,
                              void* d_out, int out_size, void* d_ws, size_t ws_size,
                              hipStream_t stream) {
  const float* noise = (const float*)d_in[0];
  const float* eps   = (const float*)d_in[1];
  const float* Wx    = (const float*)d_in[2];
  const float* Wh    = (const float*)d_in[3];
  const float* bg    = (const float*)d_in[4];
  const float* Wm1   = (const float*)d_in[5];
  const float* bm1   = (const float*)d_in[6];
  const float* Wm2   = (const float*)d_in[7];
  const float* bm2   = (const float*)d_in[8];
  const float* Wm3   = (const float*)d_in[9];
  const float* bm3   = (const float*)d_in[10];
  const float* Wv1   = (const float*)d_in[11];
  const float* bv1   = (const float*)d_in[12];
  const float* Wv2   = (const float*)d_in[13];
  const float* bv2   = (const float*)d_in[14];
  const float* Wv3   = (const float*)d_in[15];
  const float* bv3   = (const float*)d_in[16];
  float* out = (float*)d_out;

  dim3 grid(4096 / R), block(BLK);
  hipLaunchKernelGGL(genlstm_kernel, grid, block, 0, stream,
                     noise, eps, Wx, Wh, bg, Wm1, bm1, Wm2, bm2, Wm3, bm3,
                     Wv1, bv1, Wv2, bv2, Wv3, bv3, out);
}

// Round 11
// 544.748 us; speedup vs baseline: 1.7428x; 1.1495x over previous
//
#include <hip/hip_runtime.h>

typedef _Float16 half8 __attribute__((ext_vector_type(8)));
typedef _Float16 half4 __attribute__((ext_vector_type(4)));
typedef float f32x4 __attribute__((ext_vector_type(4)));

#define TSTEPS 255
#define R 16
#define BLK 512
#define XSH 104   // input-plane stride (halves): [h(0:64)|x(64:72)|noise(72:88)|zero(88:96)|pad]
#define ASH 72    // a-plane stride (halves)

__device__ __forceinline__ float frcp(float x) { return __builtin_amdgcn_rcpf(x); }

__device__ __forceinline__ f32x4 mfma16(half8 a, half8 b, f32x4 c) {
  return __builtin_amdgcn_mfma_f32_16x16x32_f16(a, b, c, 0, 0, 0);
}

__global__ __launch_bounds__(BLK)
void genlstm_kernel(const float* __restrict__ noise,
                    const float* __restrict__ eps,
                    const float* __restrict__ Wx,
                    const float* __restrict__ Wh,
                    const float* __restrict__ bg,
                    const float* __restrict__ Wm1, const float* __restrict__ bm1,
                    const float* __restrict__ Wm2, const float* __restrict__ bm2,
                    const float* __restrict__ Wm3, const float* __restrict__ bm3,
                    const float* __restrict__ Wv1, const float* __restrict__ bv1,
                    const float* __restrict__ Wv2, const float* __restrict__ bv2,
                    const float* __restrict__ Wv3, const float* __restrict__ bv3,
                    float* __restrict__ out)
{
  // parity-double-buffered input planes (h|x|noise|zero), hi/lo f16
  __shared__ __align__(16) _Float16 xh[2][R][XSH];
  __shared__ __align__(16) _Float16 xl[2][R][XSH];
  __shared__ __align__(16) _Float16 a1h[2][R][ASH];
  __shared__ __align__(16) _Float16 a1l[2][R][ASH];
  __shared__ __align__(16) _Float16 a2h[2][R][ASH];
  __shared__ __align__(16) _Float16 a2l[2][R][ASH];

  const int tid  = threadIdx.x;
  const int w    = tid >> 6;   // wave 0..7
  const int l    = tid & 63;
  const int lrow = l & 15;     // tile row/col within 16x16
  const int lq   = l >> 4;     // k-group (8 elems)
  const long rowbase = (long)blockIdx.x * R;

  // ---------- one-time weight fragment staging ----------
  // TRANSPOSED gate: A[gate-row g][k] = Wcat_r[k][ 64*(g&3) + (g>>2) ],
  // k reordered [Wh 0..63 | Wx-x 0..7 | Wx-noise 8..23 | zero].
  // Wave w owns gate-row tiles T=2w,2w+1. C: row 4lq+kk = (hc=4T+lq, gate=kk), col=lrow=batch.
  half8 gAhi[2][3], gAlo[2][3];
  #pragma unroll
  for (int t = 0; t < 2; ++t) {
    const int T = 2 * w + t;
    const int n = 64 * (lrow & 3) + 4 * T + (lrow >> 2);
    #pragma unroll
    for (int kt = 0; kt < 3; ++kt)
      #pragma unroll
      for (int j = 0; j < 8; ++j) {
        int k = 32 * kt + 8 * lq + j;
        float v = 0.f;
        if (k < 64) v = Wh[k * 256 + n];
        else if (k < 88) v = Wx[(k - 64) * 256 + n];
        _Float16 h = (_Float16)v;
        gAhi[t][kt][j] = h;
        gAlo[t][kt][j] = (_Float16)(v - (float)h);
      }
  }

  // MLP tiles (original orientation): chain = w>>2 (0:mu 1:var), N-tile nt = w&3
  const int chain = w >> 2;
  const int nt = w & 3;
  const float* W1 = chain ? Wv1 : Wm1;
  const float* W2 = chain ? Wv2 : Wm2;
  half8 B1hi[2], B1lo[2], B2hi[2], B2lo[2];
  #pragma unroll
  for (int kt = 0; kt < 2; ++kt)
    #pragma unroll
    for (int j = 0; j < 8; ++j) {
      int k = 32 * kt + 8 * lq + j;
      int n = 16 * nt + lrow;
      float v1 = W1[k * 64 + n];
      _Float16 h1 = (_Float16)v1;
      B1hi[kt][j] = h1; B1lo[kt][j] = (_Float16)(v1 - (float)h1);
      float v2 = W2[k * 64 + n];
      _Float16 h2 = (_Float16)v2;
      B2hi[kt][j] = h2; B2lo[kt][j] = (_Float16)(v2 - (float)h2);
    }

  // Transposed heads (used by wave 0 only): A[d][k] = W3[k*8+d], d>=8 zero-padded
  half8 Amhi[2], Amlo[2], Avhi[2], Avlo[2];
  #pragma unroll
  for (int kt = 0; kt < 2; ++kt)
    #pragma unroll
    for (int j = 0; j < 8; ++j) {
      int k = 32 * kt + 8 * lq + j;
      float vm = (lrow < 8) ? Wm3[k * 8 + lrow] : 0.f;
      _Float16 hm = (_Float16)vm;
      Amhi[kt][j] = hm; Amlo[kt][j] = (_Float16)(vm - (float)hm);
      float vv = (lrow < 8) ? Wv3[k * 8 + lrow] : 0.f;
      _Float16 hv = (_Float16)vv;
      Avhi[kt][j] = hv; Avlo[kt][j] = (_Float16)(vv - (float)hv);
    }

  const float bias1 = (chain ? bv1 : bm1)[16 * nt + lrow];
  const float bias2 = (chain ? bv2 : bm2)[16 * nt + lrow];

  // lane owns gate quads of h-cols hc1, hc2 (batch row lrow)
  const int hc1 = 8 * w + lq, hc2 = hc1 + 4;
  const float4 bgA = {bg[hc1], bg[64 + hc1], bg[128 + hc1], bg[192 + hc1]};
  const float4 bgB = {bg[hc2], bg[64 + hc2], bg[128 + hc2], bg[192 + hc2]};

  // head/sampler mapping (wave 0, lanes lq<2): (r=lrow, dims d0..d0+3)
  const int d0 = 4 * (lq & 1);
  const float4 bm3q = *(const float4*)&bm3[d0];
  const float4 bv3q = *(const float4*)&bv3[d0];

  float cst0 = 0.f, cst1 = 0.f;   // c-state (lrow, hc1), (lrow, hc2)
  f32x4 cum4 = {0.f, 0.f, 0.f, 0.f};
  float4 ep4 = {0.f, 0.f, 0.f, 0.f};

  // persistent h fragments (h0=0); loaded in S2, reused as S0's B-operand next step
  half8 hHi[2], hLo[2];
  #pragma unroll
  for (int kt = 0; kt < 2; ++kt)
    #pragma unroll
    for (int j = 0; j < 8; ++j) { hHi[kt][j] = (_Float16)0; hLo[kt][j] = (_Float16)0; }

  // ---------- prologue ----------
  for (int i = tid; i < 2 * R * XSH; i += BLK) {
    (&xh[0][0][0])[i] = (_Float16)0;
    (&xl[0][0][0])[i] = (_Float16)0;
  }
  {
    const int r5 = tid >> 3, d5 = tid & 7;
    if (tid < 128) out[((rowbase + r5) * 256) * 8 + d5] = 0.f;  // cumsum row 0
  }

  float4 nz = {0.f, 0.f, 0.f, 0.f};
  if (tid < 64) {   // noise[0] -> buf[0]
    int r = tid >> 2, j4 = (tid & 3) * 4;
    float4 n0 = *(const float4*)&noise[((rowbase + r) * TSTEPS) * 16 + j4];
    float tmp[4] = {n0.x, n0.y, n0.z, n0.w};
    half4 nh, nl;
    #pragma unroll
    for (int j = 0; j < 4; ++j) {
      _Float16 h = (_Float16)tmp[j];
      nh[j] = h; nl[j] = (_Float16)(tmp[j] - (float)h);
    }
    *(half4*)&xh[0][r][72 + j4] = nh;
    *(half4*)&xl[0][r][72 + j4] = nl;
    nz = *(const float4*)&noise[((rowbase + r) * TSTEPS + 1) * 16 + j4];
  }
  if (w == 0 && lq < 2)
    ep4 = *(const float4*)&eps[((rowbase + lrow) * TSTEPS) * 8 + d0];
  __syncthreads();

  // ---------- time loop: 4 barriers/step ----------
  for (int ts = 0; ts < TSTEPS; ++ts) {
    const int p = ts & 1, p1 = p ^ 1;

    // ---- S0: transposed gate MFMA -> gate quads land in registers.
    // B kt0/kt1 = h (register-resident), kt2 = x|noise from buf[p].
    half8 Xhi = *(const half8*)&xh[p][lrow][64 + 8 * lq];
    half8 Xlo = *(const half8*)&xl[p][lrow][64 + 8 * lq];

    f32x4 az0 = {0.f, 0.f, 0.f, 0.f};
    f32x4 az1 = {0.f, 0.f, 0.f, 0.f};
    az0 = mfma16(gAhi[0][0], hHi[0], az0);
    az1 = mfma16(gAhi[1][0], hHi[0], az1);
    az0 = mfma16(gAlo[0][0], hHi[0], az0);
    az1 = mfma16(gAlo[1][0], hHi[0], az1);
    az0 = mfma16(gAhi[0][0], hLo[0], az0);
    az1 = mfma16(gAhi[1][0], hLo[0], az1);
    az0 = mfma16(gAhi[0][1], hHi[1], az0);
    az1 = mfma16(gAhi[1][1], hHi[1], az1);
    az0 = mfma16(gAlo[0][1], hHi[1], az0);
    az1 = mfma16(gAlo[1][1], hHi[1], az1);
    az0 = mfma16(gAhi[0][1], hLo[1], az0);
    az1 = mfma16(gAhi[1][1], hLo[1], az1);
    az0 = mfma16(gAhi[0][2], Xhi, az0);
    az1 = mfma16(gAhi[1][2], Xhi, az1);
    az0 = mfma16(gAlo[0][2], Xhi, az0);
    az1 = mfma16(gAlo[1][2], Xhi, az1);
    az0 = mfma16(gAhi[0][2], Xlo, az0);
    az1 = mfma16(gAhi[1][2], Xlo, az1);

    // ---- S1 (no barrier): gate nonlinearity from registers; h -> buf[p1]
    {
      float zi = az0[0] + bgA.x, zf = az0[1] + bgA.y;
      float zg = az0[2] + bgA.z, zo = az0[3] + bgA.w;
      float si = frcp(1.f + __expf(-zi));
      float sf = frcp(1.f + __expf(-zf));
      float so = frcp(1.f + __expf(-zo));
      float ag = fabsf(zg), eg = __expf(-2.f * ag);
      float tg = copysignf((1.f - eg) * frcp(1.f + eg), zg);
      cst0 = fmaf(sf, cst0, si * tg);
      float ac = fabsf(cst0), ec = __expf(-2.f * ac);
      float tc = copysignf((1.f - ec) * frcp(1.f + ec), cst0);
      float hv = so * tc;
      _Float16 hh = (_Float16)hv;
      xh[p1][lrow][hc1] = hh;
      xl[p1][lrow][hc1] = (_Float16)(hv - (float)hh);
    }
    {
      float zi = az1[0] + bgB.x, zf = az1[1] + bgB.y;
      float zg = az1[2] + bgB.z, zo = az1[3] + bgB.w;
      float si = frcp(1.f + __expf(-zi));
      float sf = frcp(1.f + __expf(-zf));
      float so = frcp(1.f + __expf(-zo));
      float ag = fabsf(zg), eg = __expf(-2.f * ag);
      float tg = copysignf((1.f - eg) * frcp(1.f + eg), zg);
      cst1 = fmaf(sf, cst1, si * tg);
      float ac = fabsf(cst1), ec = __expf(-2.f * ac);
      float tc = copysignf((1.f - ec) * frcp(1.f + ec), cst1);
      float hv = so * tc;
      _Float16 hh = (_Float16)hv;
      xh[p1][lrow][hc2] = hh;
      xl[p1][lrow][hc2] = (_Float16)(hv - (float)hh);
    }
    if (tid < 64) {   // noise[ts+1] -> buf[p1]; prefetch noise[ts+2]
      int r = tid >> 2, j4 = (tid & 3) * 4;
      float tmp[4] = {nz.x, nz.y, nz.z, nz.w};
      half4 nh, nl;
      #pragma unroll
      for (int j = 0; j < 4; ++j) {
        _Float16 h = (_Float16)tmp[j];
        nh[j] = h; nl[j] = (_Float16)(tmp[j] - (float)h);
      }
      *(half4*)&xh[p1][r][72 + j4] = nh;
      *(half4*)&xl[p1][r][72 + j4] = nl;
      if (ts + 2 < TSTEPS)
        nz = *(const float4*)&noise[((rowbase + r) * TSTEPS + ts + 2) * 16 + j4];
    }
    __syncthreads();  // B: h[ts] + noise[ts+1] complete in buf[p1]

    // ---- S2: MLP layer 1 (h frags loaded here feed next step's S0)
    {
      hHi[0] = *(const half8*)&xh[p1][lrow][8 * lq];
      hHi[1] = *(const half8*)&xh[p1][lrow][32 + 8 * lq];
      hLo[0] = *(const half8*)&xl[p1][lrow][8 * lq];
      hLo[1] = *(const half8*)&xl[p1][lrow][32 + 8 * lq];
      f32x4 acc = {0.f, 0.f, 0.f, 0.f};
      #pragma unroll
      for (int kt = 0; kt < 2; ++kt) {
        acc = mfma16(hHi[kt], B1hi[kt], acc);
        acc = mfma16(hLo[kt], B1hi[kt], acc);
        acc = mfma16(hHi[kt], B1lo[kt], acc);
      }
      const int r0 = 4 * lq;
      #pragma unroll
      for (int k = 0; k < 4; ++k) {
        float v = fmaxf(acc[k] + bias1, 0.f);
        _Float16 vh = (_Float16)v;
        a1h[chain][r0 + k][16 * nt + lrow] = vh;
        a1l[chain][r0 + k][16 * nt + lrow] = (_Float16)(v - (float)vh);
      }
    }
    __syncthreads();  // C

    // ---- S3: MLP layer 2
    {
      half8 ahi0 = *(const half8*)&a1h[chain][lrow][8 * lq];
      half8 ahi1 = *(const half8*)&a1h[chain][lrow][32 + 8 * lq];
      half8 alo0 = *(const half8*)&a1l[chain][lrow][8 * lq];
      half8 alo1 = *(const half8*)&a1l[chain][lrow][32 + 8 * lq];
      f32x4 acc = {0.f, 0.f, 0.f, 0.f};
      acc = mfma16(ahi0, B2hi[0], acc);
      acc = mfma16(alo0, B2hi[0], acc);
      acc = mfma16(ahi0, B2lo[0], acc);
      acc = mfma16(ahi1, B2hi[1], acc);
      acc = mfma16(alo1, B2hi[1], acc);
      acc = mfma16(ahi1, B2lo[1], acc);
      const int r0 = 4 * lq;
      #pragma unroll
      for (int k = 0; k < 4; ++k) {
        float v = fmaxf(acc[k] + bias2, 0.f);
        _Float16 vh = (_Float16)v;
        a2h[chain][r0 + k][16 * nt + lrow] = vh;
        a2l[chain][r0 + k][16 * nt + lrow] = (_Float16)(v - (float)vh);
      }
    }
    __syncthreads();  // D: a2 complete

    // ---- S4+S5: head + sample + out + x feedback, wave 0 only
    if (w == 0) {
      half8 b0h0 = *(const half8*)&a2h[0][lrow][8 * lq];
      half8 b0h1 = *(const half8*)&a2h[0][lrow][32 + 8 * lq];
      half8 b0l0 = *(const half8*)&a2l[0][lrow][8 * lq];
      half8 b0l1 = *(const half8*)&a2l[0][lrow][32 + 8 * lq];
      f32x4 accm = {0.f, 0.f, 0.f, 0.f};
      accm = mfma16(Amhi[0], b0h0, accm);
      accm = mfma16(Amlo[0], b0h0, accm);
      accm = mfma16(Amhi[0], b0l0, accm);
      accm = mfma16(Amhi[1], b0h1, accm);
      accm = mfma16(Amlo[1], b0h1, accm);
      accm = mfma16(Amhi[1], b0l1, accm);
      half8 b1h0 = *(const half8*)&a2h[1][lrow][8 * lq];
      half8 b1h1 = *(const half8*)&a2h[1][lrow][32 + 8 * lq];
      half8 b1l0 = *(const half8*)&a2l[1][lrow][8 * lq];
      half8 b1l1 = *(const half8*)&a2l[1][lrow][32 + 8 * lq];
      f32x4 accv = {0.f, 0.f, 0.f, 0.f};
      accv = mfma16(Avhi[0], b1h0, accv);
      accv = mfma16(Avlo[0], b1h0, accv);
      accv = mfma16(Avhi[0], b1l0, accv);
      accv = mfma16(Avhi[1], b1h1, accv);
      accv = mfma16(Avlo[1], b1h1, accv);
      accv = mfma16(Avhi[1], b1l1, accv);

      float xs0 = fmaf(__expf(0.5f * (accv[0] + bv3q.x)), ep4.x, accm[0] + bm3q.x);
      float xs1 = fmaf(__expf(0.5f * (accv[1] + bv3q.y)), ep4.y, accm[1] + bm3q.y);
      float xs2 = fmaf(__expf(0.5f * (accv[2] + bv3q.z)), ep4.z, accm[2] + bm3q.z);
      float xs3 = fmaf(__expf(0.5f * (accv[3] + bv3q.w)), ep4.w, accm[3] + bm3q.w);
      cum4[0] += xs0; cum4[1] += xs1; cum4[2] += xs2; cum4[3] += xs3;
      if (lq < 2) {
        float4 cv = {cum4[0], cum4[1], cum4[2], cum4[3]};
        *(float4*)&out[((rowbase + lrow) * 256 + ts + 1) * 8 + d0] = cv;
        float xs[4] = {xs0, xs1, xs2, xs3};
        half4 xhv, xlv;
        #pragma unroll
        for (int j = 0; j < 4; ++j) {
          _Float16 hh = (_Float16)xs[j];
          xhv[j] = hh; xlv[j] = (_Float16)(xs[j] - (float)hh);
        }
        *(half4*)&xh[p1][lrow][64 + d0] = xhv;
        *(half4*)&xl[p1][lrow][64 + d0] = xlv;
        if (ts + 1 < TSTEPS)
          ep4 = *(const float4*)&eps[((rowbase + lrow) * TSTEPS + ts + 1) * 8 + d0];
      }
    }
    __syncthreads();  // E: x[ts] in buf[p1]; next S0 reads buf[p1]
  }
}

extern "C" void kernel_launch(void* const* d_in, const int* in_sizes, int n_in,
                              void* d_out, int out_size, void* d_ws, size_t ws_size,
                              hipStream_t stream) {
  const float* noise = (const float*)d_in[0];
  const float* eps   = (const float*)d_in[1];
  const float* Wx    = (const float*)d_in[2];
  const float* Wh    = (const float*)d_in[3];
  const float* bg    = (const float*)d_in[4];
  const float* Wm1   = (const float*)d_in[5];
  const float* bm1   = (const float*)d_in[6];
  const float* Wm2   = (const float*)d_in[7];
  const float* bm2   = (const float*)d_in[8];
  const float* Wm3   = (const float*)d_in[9];
  const float* bm3   = (const float*)d_in[10];
  const float* Wv1   = (const float*)d_in[11];
  const float* bv1   = (const float*)d_in[12];
  const float* Wv2   = (const float*)d_in[13];
  const float* bv2   = (const float*)d_in[14];
  const float* Wv3   = (const float*)d_in[15];
  const float* bv3   = (const float*)d_in[16];
  float* out = (float*)d_out;

  dim3 grid(4096 / R), block(BLK);
  hipLaunchKernelGGL(genlstm_kernel, grid, block, 0, stream,
                     noise, eps, Wx, Wh, bg, Wm1, bm1, Wm2, bm2, Wm3, bm3,
                     Wv1, bv1, Wv2, bv2, Wv3, bv3, out);
}